// Round 6
// baseline (726.319 us; speedup 1.0000x reference)
//
#include <hip/hip_runtime.h>

typedef __attribute__((ext_vector_type(8))) short short8;
typedef __attribute__((ext_vector_type(4))) float f32x4;
typedef __attribute__((ext_vector_type(4))) unsigned short us4;

#define LEAK 0.2f

__device__ __forceinline__ float b2f(unsigned short s) {
    unsigned u = ((unsigned)s) << 16;
    return __builtin_bit_cast(float, u);
}
__device__ __forceinline__ unsigned short f2b(float f) {
    unsigned u = __builtin_bit_cast(unsigned, f);
    u += 0x7fffu + ((u >> 16) & 1u);
    return (unsigned short)(u >> 16);
}

// async 16B global->LDS (direct-to-shared DMA). LDS base wave-uniform; HW adds lane*16.
__device__ __forceinline__ void async16(const short* g, short* l) {
    __builtin_amdgcn_global_load_lds(
        (const __attribute__((address_space(1))) void*)g,
        (__attribute__((address_space(3))) void*)l, 16, 0, 0);
}

// ---------------- prep: upsample / warp / cost volume (LDS-staged, coalesced) ----
// Block = 64 pixels of one row (quarter row). All global I/O is 16B/lane contiguous.
// vol: halo layout [B,130,258,144] bf16; interior pixel (h,w) -> row h+1, col w+1.
// ch 0..127 = left(bf16), 128..132 = costs, 133 = up, 134..143 = 0.
__global__ __launch_bounds__(256)
void prep_kernel(const float* __restrict__ left, const float* __restrict__ right,
                 const float* __restrict__ pd, short* __restrict__ vol) {
    __shared__ __align__(16) float inL[64 * 132];   // [px][128 ch + 4 pad]
    __shared__ __align__(16) float rrow[256];       // right row (b,h)
    __shared__ __align__(16) float pr0[128];        // pd row y0c
    __shared__ __align__(16) float pr1[128];        // pd row y1c
    __shared__ __align__(16) short outT[64 * 144];  // output tile

    int t = threadIdx.x;
    int blk = blockIdx.x;                 // 4096 = b(8) * h(128) * wq(4)
    int wq = blk & 3, h = (blk >> 2) & 127, b = blk >> 9;
    int w0 = wq << 6;

    // row-uniform upsample y terms
    float sy = h * 0.5f - 0.25f;
    float fy0 = floorf(sy);
    float fy = sy - fy0;
    int y0 = (int)fy0;
    int y0c = min(max(y0, 0), 63), y1c = min(max(y0 + 1, 0), 63);

    // ---- phase 1: coalesced loads -> LDS ----
    const float* lp = left + ((size_t)((b * 128 + h) * 256 + w0)) * 128;
#pragma unroll
    for (int k2 = 0; k2 < 8; ++k2) {
        int g = t + k2 * 256;             // granule 0..2047 (16B each)
        int p = g >> 5, j = g & 31;
        float4 v = *(const float4*)(lp + (size_t)g * 4);
        *(float4*)(&inL[p * 132 + j * 4]) = v;
    }
    if (t < 64) {
        *(float4*)(&rrow[t * 4]) =
            *(const float4*)(right + ((size_t)(b * 128 + h)) * 256 + t * 4);
    } else if (t < 96) {
        int i2 = t - 64;
        *(float4*)(&pr0[i2 * 4]) = *(const float4*)(pd + (size_t)(b * 64 + y0c) * 128 + i2 * 4);
    } else if (t < 128) {
        int i2 = t - 96;
        *(float4*)(&pr1[i2 * 4]) = *(const float4*)(pd + (size_t)(b * 64 + y1c) * 128 + i2 * 4);
    }
    __syncthreads();

    // ---- phase 2: 4 threads per pixel ----
    int p = t >> 2, s = t & 3;
    int w = w0 + p;
    const float* src = &inL[p * 132 + s * 32];
    short* odst = &outT[p * 144 + s * 32];
    float sum = 0.f;
#pragma unroll
    for (int i = 0; i < 8; ++i) {
        float f0 = src[i * 4], f1 = src[i * 4 + 1], f2 = src[i * 4 + 2], f3 = src[i * 4 + 3];
        sum += (f0 + f1) + (f2 + f3);
        us4 o;
        o.x = f2b(f0); o.y = f2b(f1); o.z = f2b(f2); o.w = f2b(f3);
        *(us4*)(odst + i * 4) = o;
    }
    sum += __shfl_xor(sum, 1);
    sum += __shfl_xor(sum, 2);
    float mean = sum * (1.f / 128.f);

    float one_fy = 1.f - fy;
#pragma unroll
    for (int tap = s; tap < 5; tap += 4) {   // s=0 -> taps 0,4; s=1,2,3 -> taps 1,2,3
        int jj = w + tap - 2;
        if (jj >= 0 && jj < 256) {
            float sx = jj * 0.5f - 0.25f;
            float fx0 = floorf(sx);
            float fx = sx - fx0;
            int x0 = (int)fx0;
            int x0c = min(max(x0, 0), 127), x1c = min(max(x0 + 1, 0), 127);
            float up = one_fy * ((1.f - fx) * pr0[x0c] + fx * pr0[x1c])
                     + fy     * ((1.f - fx) * pr1[x0c] + fx * pr1[x1c]);
            float cx = (float)jj - up;
            float xf0 = floorf(cx), xf1 = xf0 + 1.f;
            float w0x = xf1 - cx, w1x = cx - xf0;
            int ix0 = (int)fminf(fmaxf(xf0, 0.f), 255.f);
            int ix1 = (int)fminf(fmaxf(xf1, 0.f), 255.f);
            float warped = w0x * rrow[ix0] + w1x * rrow[ix1];
            outT[p * 144 + 128 + tap] = (short)f2b(warped * mean);
            if (tap == 2) outT[p * 144 + 133] = (short)f2b(up);   // jj==w always in-range
        } else {
            outT[p * 144 + 128 + tap] = 0;
        }
    }
    if (s == 0) { outT[p * 144 + 134] = 0; outT[p * 144 + 135] = 0; }
    if (s == 3) {
        us4 z = {};
        *(us4*)(&outT[p * 144 + 136]) = z;
        *(us4*)(&outT[p * 144 + 140]) = z;
    }
    __syncthreads();

    // ---- phase 3: coalesced store (tile is contiguous in halo layout) ----
    short* gdst = vol + ((size_t)(b * 130 + h + 1) * 258 + (w0 + 1)) * 144;
    for (int g = t; g < 1152; g += 256)
        *(short8*)(gdst + g * 8) = *(const short8*)(&outT[g * 8]);
}

// zero the halo ring of ONE buffer (schedule AFTER last reader of aliased layout)
__global__ void halo_zero_one(short* __restrict__ buf, int C) {
    int nchunk = C >> 3;
    int slot = blockIdx.x * 256 + threadIdx.x;
    int total = 8 * 772 * nchunk;
    if (slot >= total) return;
    int chunk = slot % nchunk;
    int pix = slot / nchunk;
    int b = pix / 772, p = pix % 772;
    int row, col;
    if (p < 516) { row = (p < 258) ? 0 : 129; col = (p < 258) ? p : p - 258; }
    else { int q = p - 516; row = 1 + (q >> 1); col = (q & 1) ? 257 : 0; }
    short8 z = {};
    *(short8*)(buf + ((size_t)(b * 130 + row) * 258 + col) * C + chunk * 8) = z;
}

// fp32 HWIO weights -> bf16 swizzled layout, all 5 layers in one launch.
// Layout (shorts): granule g = ((kc*9+tap)*COUT + n)*4 + s, where slot s holds
// k-quarter q = (s - (n>>1)) & 3; within granule, 8 consecutive k (q*8..q*8+7).
// k zero-padded past CIN. Staged to LDS as identity copy (legal for
// global_load_lds); read with slot=(q+(n>>1))&3.
// WHY >>1: LDS serves a wave64 ds_read_b128 in quarter-wave phases of 16 lanes
// with q CONSTANT inside a phase; granule%8 = 4*(n&1) + slot must walk all 8
// bank groups as col=n&15 varies. slot=(q+(n>>1))&3 does; slot=(q+n)&3 does
// NOT (4 groups, 4-way conflict) -- verified round 4: conflicts 8.85M -> 0.
__global__ void wconv_all(const float* __restrict__ k1, const float* __restrict__ k2,
                          const float* __restrict__ k3, const float* __restrict__ k4,
                          const float* __restrict__ k5,
                          short* __restrict__ w1, short* __restrict__ w2,
                          short* __restrict__ w3, short* __restrict__ w4,
                          short* __restrict__ w5) {
    const int CINt[5]  = {134, 128, 128, 96, 64};
    const int COUTt[5] = {128, 128, 96, 64, 32};
    const int KCt[5]   = {5, 4, 4, 3, 2};
    const float* srcs[5] = {k1, k2, k3, k4, k5};
    short* dsts[5] = {w1, w2, w3, w4, w5};
    int l = blockIdx.y;
    int CIN = CINt[l], COUT = COUTt[l], KC = KCt[l];
    const float* k = srcs[l];
    short* wt = dsts[l];
    int idx = blockIdx.x * 256 + threadIdx.x;
    int total = 9 * KC * COUT * 32;
    if (idx >= total) return;
    int j = idx & 7;
    int s = (idx >> 3) & 3;
    int rest = idx >> 5;              // (kc*9+tap)*COUT + n
    int n = rest % COUT; rest /= COUT;
    int tap = rest % 9, kc = rest / 9;
    int q = (s - (n >> 1)) & 3;
    int kk = q * 8 + j;
    int ci = kc * 32 + kk;
    float v = (ci < CIN) ? k[(size_t)(tap * CIN + ci) * COUT + n] : 0.f;
    wt[idx] = (short)f2b(v);
}

// 3x3 SAME conv, halo layout [B,130,258,CIN_STR] -> [B,130,258,COUT].
// OCCUPANCY design point (rounds 0/4/5 all stuck at 27-29k cy/kc with 2
// waves/SIMD: 248 unified regs/wave = the pin; staging schedule irrelevant).
// Block: 512 thr = 8 waves = (4 out rows) x (2 n-halves); tile 4x64 px x COUT.
// acc[4][NT<=4] = 64 f32 -> ~115 regs/wave; __launch_bounds__(512,4) caps 128
// -> 4 waves/SIMD. LDS: A single 6x66x32ch = 25,344 B + W per-dy slice
// 3*COUT*32 sh (<=24,576 B) = 49,920 B -> 2 blocks/CU CO-RESIDENT: the other
// block's compute hides every stage+drain (TLP, not manual pipelining -- the
// r2 lesson applied leanly: no dbuf, no prefetch lambdas, no XCD remap).
// Both >>1 phase-correct swizzles kept (r4-verified: conflicts 8.85M -> 0).
template <int KC, int CIN_STR, int COUT, int NT, int LASTC>
__launch_bounds__(512, 4)
__global__ void conv3x3_kernel(const short* __restrict__ in, const short* __restrict__ wt,
                               const float* __restrict__ bias, short* __restrict__ out) {
    __shared__ short ldsA[6 * 66 * 4 * 8];       // 25,344 B
    __shared__ short ldsW[3 * COUT * 32];        // per-dy slice; COUT=128: 24,576 B
    const int NH = COUT / 2;
    const int WSLOTS = COUT * 12;                // 16B granules per dy slice

    int t = threadIdx.x;
    int lane = t & 63, wid = t >> 6;
    int q = lane >> 4, col = lane & 15;
    int r = wid & 3, h = wid >> 2;               // wave = out-row r, n-half h

    int wtile = blockIdx.x & 3;
    int rest = blockIdx.x >> 2;
    int htile = rest & 31, b = rest >> 5;
    int w0h = wtile << 6;                        // staged cols w0h .. w0h+65
    int row0 = htile << 2;                       // staged rows row0 .. row0+5

    const short* inbase = in + ((size_t)(b * 130 + row0) * 258 + w0h) * CIN_STR;

    f32x4 acc[4][NT] = {};

    for (int kc = 0; kc < KC; ++kc) {
#pragma unroll
        for (int dy = 0; dy < 3; ++dy) {
            if (kc | dy) __syncthreads();        // prev readers of ldsA/ldsW done
            if (dy == 0) {
                // stage A chunk kc: 1584 granules (rr*264 + p*4 + s),
                // slot s holds channel-chunk c = (s-(p>>1))&3
                for (int i = t; i < 1584; i += 512) {
                    int rr = i / 264, rem = i % 264;
                    int p = rem >> 2, s = rem & 3;
                    int c = (s - (p >> 1)) & 3;
                    if (LASTC == 4 || kc < KC - 1 || c < LASTC) {
                        const short* g = inbase + ((size_t)rr * 258 + p) * CIN_STR
                                       + kc * 32 + c * 8;
                        async16(g, ldsA + (size_t)(i & ~63) * 8);
                    }
                }
            }
            // stage W dy-slice (taps 3*dy..3*dy+2): identity copy, pre-swizzled
            {
                const short* wsrc = wt + (size_t)(kc * 9 + dy * 3) * COUT * 32;
                for (int i = t; i < WSLOTS; i += 512)
                    async16(wsrc + (size_t)i * 8, ldsW + (size_t)(i & ~63) * 8);
            }
            __syncthreads();                     // staged data visible

            int ldsrow = r + dy;
#pragma unroll
            for (int dx = 0; dx < 3; ++dx) {
                short8 a[4], bfr[NT];
#pragma unroll
                for (int mt = 0; mt < 4; ++mt) {
                    int p = mt * 16 + col + dx;
                    a[mt] = *(const short8*)(ldsA +
                        (size_t)(((ldsrow * 66 + p) << 2) + ((q + (p >> 1)) & 3)) * 8);
                }
#pragma unroll
                for (int nt = 0; nt < NT; ++nt) {
                    int n = h * NH + nt * 16 + col;
                    bfr[nt] = *(const short8*)(ldsW +
                        (size_t)(((dx * COUT + n) << 2) + ((q + (n >> 1)) & 3)) * 8);
                }
#pragma unroll
                for (int mt = 0; mt < 4; ++mt)
#pragma unroll
                    for (int nt = 0; nt < NT; ++nt)
                        acc[mt][nt] = __builtin_amdgcn_mfma_f32_16x16x32_bf16(
                            a[mt], bfr[nt], acc[mt][nt], 0, 0, 0);
            }
        }
    }

    // ---- epilogue: D[m = mt*16 + q*4 + rr][n = h*NH + nt*16 + col] ----
    size_t obase = ((size_t)(b * 130 + row0 + 1 + r) * 258 + (w0h + 1)) * COUT + h * NH;
#pragma unroll
    for (int nt = 0; nt < NT; ++nt) {
        float bv = bias[h * NH + nt * 16 + col];
#pragma unroll
        for (int mt = 0; mt < 4; ++mt) {
#pragma unroll
            for (int rr = 0; rr < 4; ++rr) {
                int m = mt * 16 + q * 4 + rr;
                float v = acc[mt][nt][rr] + bv;
                v = (v >= 0.f) ? v : LEAK * v;
                out[obase + (size_t)m * COUT + nt * 16 + col] = (short)f2b(v);
            }
        }
    }
}

// conv6: 3x3, Cin=32 (halo layout), Cout=1, linear, fp32 out (flat [B,H,W])
__global__ void conv6_kernel(const short* __restrict__ x, const float* __restrict__ k,
                             const float* __restrict__ bias, float* __restrict__ out) {
    __shared__ float wk[288];
    int t = threadIdx.x;
    for (int i = t; i < 288; i += 256) wk[i] = k[i];
    __syncthreads();
    int idx = blockIdx.x * 256 + t;
    int w = idx & 255, h = (idx >> 8) & 127, b = idx >> 15;
    float acc = bias[0];
#pragma unroll
    for (int dy = 0; dy < 3; ++dy) {
#pragma unroll
        for (int dx = 0; dx < 3; ++dx) {
            const short* xp = x + ((size_t)(b * 130 + h + dy) * 258 + (w + dx)) * 32;
            const float* wp = wk + (dy * 3 + dx) * 32;
#pragma unroll
            for (int c8 = 0; c8 < 4; ++c8) {
                short8 v = *(const short8*)(xp + c8 * 8);
#pragma unroll
                for (int j = 0; j < 8; ++j)
                    acc += b2f((unsigned short)v[j]) * wp[c8 * 8 + j];
            }
        }
    }
    out[idx] = acc;
}

extern "C" void kernel_launch(void* const* d_in, const int* in_sizes, int n_in,
                              void* d_out, int out_size, void* d_ws, size_t ws_size,
                              hipStream_t stream) {
    const float* left  = (const float*)d_in[0];
    const float* right = (const float*)d_in[1];
    const float* pd    = (const float*)d_in[2];
    const float* k[6];
    const float* bb[6];
    for (int i = 0; i < 6; ++i) { k[i] = (const float*)d_in[3 + 2 * i]; bb[i] = (const float*)d_in[4 + 2 * i]; }

    char* ws = (char*)d_ws;
    // weights: [0, 1 MiB)
    short* wt1 = (short*)ws;
    short* wt2 = (short*)(ws + 368640);
    short* wt3 = (short*)(ws + 663552);
    short* wt4 = (short*)(ws + 884736);
    short* wt5 = (short*)(ws + 995328);
    // region A @1 MiB: vol(C=144) -> X2(128) -> X4(64); region B: X1(128) -> X3(96) -> X5(32)
    short* vol = (short*)(ws + 1048576);
    short* X1  = (short*)(ws + 1048576 + 77276160);
    short* X2  = vol;
    short* X3  = X1;
    short* X4  = vol;
    short* X5  = X1;

    auto hz = [&](short* buf, int C) {
        int blocks = (8 * 772 * (C >> 3) + 255) / 256;
        halo_zero_one<<<blocks, 256, 0, stream>>>(buf, C);
    };

    prep_kernel<<<4096, 256, 0, stream>>>(left, right, pd, vol);
    wconv_all<<<dim3(720, 5), 256, 0, stream>>>(k[0], k[1], k[2], k[3], k[4],
                                                wt1, wt2, wt3, wt4, wt5);
    hz(vol, 144);
    hz(X1, 128);

    conv3x3_kernel<5, 144, 128, 4, 2><<<1024, 512, 0, stream>>>(vol, wt1, bb[0], X1);
    hz(X2, 128);   // region A: only after conv1 finished reading vol
    conv3x3_kernel<4, 128, 128, 4, 4><<<1024, 512, 0, stream>>>(X1, wt2, bb[1], X2);
    hz(X3, 96);    // region B: only after conv2 finished reading X1
    conv3x3_kernel<4, 128,  96, 3, 4><<<1024, 512, 0, stream>>>(X2, wt3, bb[2], X3);
    hz(X4, 64);    // region A: only after conv3 finished reading X2
    conv3x3_kernel<3,  96,  64, 2, 4><<<1024, 512, 0, stream>>>(X3, wt4, bb[3], X4);
    hz(X5, 32);    // region B: only after conv4 finished reading X3
    conv3x3_kernel<2,  64,  32, 1, 4><<<1024, 512, 0, stream>>>(X4, wt5, bb[4], X5);
    conv6_kernel<<<1024, 256, 0, stream>>>(X5, k[5], bb[5], (float*)d_out);
}

// Round 7
// 670.403 us; speedup vs baseline: 1.0834x; 1.0834x over previous
//
#include <hip/hip_runtime.h>

typedef __attribute__((ext_vector_type(8))) short short8;
typedef __attribute__((ext_vector_type(4))) float f32x4;
typedef __attribute__((ext_vector_type(4))) unsigned short us4;

#define LEAK 0.2f

__device__ __forceinline__ float b2f(unsigned short s) {
    unsigned u = ((unsigned)s) << 16;
    return __builtin_bit_cast(float, u);
}
__device__ __forceinline__ unsigned short f2b(float f) {
    unsigned u = __builtin_bit_cast(unsigned, f);
    u += 0x7fffu + ((u >> 16) & 1u);
    return (unsigned short)(u >> 16);
}

// async 16B global->LDS (direct-to-shared DMA). LDS base wave-uniform; HW adds lane*16.
__device__ __forceinline__ void async16(const short* g, short* l) {
    __builtin_amdgcn_global_load_lds(
        (const __attribute__((address_space(1))) void*)g,
        (__attribute__((address_space(3))) void*)l, 16, 0, 0);
}

// ---------------- prep: upsample / warp / cost volume (LDS-staged, coalesced) ----
// Block = 64 pixels of one row (quarter row). All global I/O is 16B/lane contiguous.
// vol: halo layout [B,130,258,144] bf16; interior pixel (h,w) -> row h+1, col w+1.
// ch 0..127 = left(bf16), 128..132 = costs, 133 = up, 134..143 = 0.
__global__ __launch_bounds__(256)
void prep_kernel(const float* __restrict__ left, const float* __restrict__ right,
                 const float* __restrict__ pd, short* __restrict__ vol) {
    __shared__ __align__(16) float inL[64 * 132];   // [px][128 ch + 4 pad]
    __shared__ __align__(16) float rrow[256];       // right row (b,h)
    __shared__ __align__(16) float pr0[128];        // pd row y0c
    __shared__ __align__(16) float pr1[128];        // pd row y1c
    __shared__ __align__(16) short outT[64 * 144];  // output tile

    int t = threadIdx.x;
    int blk = blockIdx.x;                 // 4096 = b(8) * h(128) * wq(4)
    int wq = blk & 3, h = (blk >> 2) & 127, b = blk >> 9;
    int w0 = wq << 6;

    // row-uniform upsample y terms
    float sy = h * 0.5f - 0.25f;
    float fy0 = floorf(sy);
    float fy = sy - fy0;
    int y0 = (int)fy0;
    int y0c = min(max(y0, 0), 63), y1c = min(max(y0 + 1, 0), 63);

    // ---- phase 1: coalesced loads -> LDS ----
    const float* lp = left + ((size_t)((b * 128 + h) * 256 + w0)) * 128;
#pragma unroll
    for (int k2 = 0; k2 < 8; ++k2) {
        int g = t + k2 * 256;             // granule 0..2047 (16B each)
        int p = g >> 5, j = g & 31;
        float4 v = *(const float4*)(lp + (size_t)g * 4);
        *(float4*)(&inL[p * 132 + j * 4]) = v;
    }
    if (t < 64) {
        *(float4*)(&rrow[t * 4]) =
            *(const float4*)(right + ((size_t)(b * 128 + h)) * 256 + t * 4);
    } else if (t < 96) {
        int i2 = t - 64;
        *(float4*)(&pr0[i2 * 4]) = *(const float4*)(pd + (size_t)(b * 64 + y0c) * 128 + i2 * 4);
    } else if (t < 128) {
        int i2 = t - 96;
        *(float4*)(&pr1[i2 * 4]) = *(const float4*)(pd + (size_t)(b * 64 + y1c) * 128 + i2 * 4);
    }
    __syncthreads();

    // ---- phase 2: 4 threads per pixel ----
    int p = t >> 2, s = t & 3;
    int w = w0 + p;
    const float* src = &inL[p * 132 + s * 32];
    short* odst = &outT[p * 144 + s * 32];
    float sum = 0.f;
#pragma unroll
    for (int i = 0; i < 8; ++i) {
        float f0 = src[i * 4], f1 = src[i * 4 + 1], f2 = src[i * 4 + 2], f3 = src[i * 4 + 3];
        sum += (f0 + f1) + (f2 + f3);
        us4 o;
        o.x = f2b(f0); o.y = f2b(f1); o.z = f2b(f2); o.w = f2b(f3);
        *(us4*)(odst + i * 4) = o;
    }
    sum += __shfl_xor(sum, 1);
    sum += __shfl_xor(sum, 2);
    float mean = sum * (1.f / 128.f);

    float one_fy = 1.f - fy;
#pragma unroll
    for (int tap = s; tap < 5; tap += 4) {   // s=0 -> taps 0,4; s=1,2,3 -> taps 1,2,3
        int jj = w + tap - 2;
        if (jj >= 0 && jj < 256) {
            float sx = jj * 0.5f - 0.25f;
            float fx0 = floorf(sx);
            float fx = sx - fx0;
            int x0 = (int)fx0;
            int x0c = min(max(x0, 0), 127), x1c = min(max(x0 + 1, 0), 127);
            float up = one_fy * ((1.f - fx) * pr0[x0c] + fx * pr0[x1c])
                     + fy     * ((1.f - fx) * pr1[x0c] + fx * pr1[x1c]);
            float cx = (float)jj - up;
            float xf0 = floorf(cx), xf1 = xf0 + 1.f;
            float w0x = xf1 - cx, w1x = cx - xf0;
            int ix0 = (int)fminf(fmaxf(xf0, 0.f), 255.f);
            int ix1 = (int)fminf(fmaxf(xf1, 0.f), 255.f);
            float warped = w0x * rrow[ix0] + w1x * rrow[ix1];
            outT[p * 144 + 128 + tap] = (short)f2b(warped * mean);
            if (tap == 2) outT[p * 144 + 133] = (short)f2b(up);   // jj==w always in-range
        } else {
            outT[p * 144 + 128 + tap] = 0;
        }
    }
    if (s == 0) { outT[p * 144 + 134] = 0; outT[p * 144 + 135] = 0; }
    if (s == 3) {
        us4 z = {};
        *(us4*)(&outT[p * 144 + 136]) = z;
        *(us4*)(&outT[p * 144 + 140]) = z;
    }
    __syncthreads();

    // ---- phase 3: coalesced store (tile is contiguous in halo layout) ----
    short* gdst = vol + ((size_t)(b * 130 + h + 1) * 258 + (w0 + 1)) * 144;
    for (int g = t; g < 1152; g += 256)
        *(short8*)(gdst + g * 8) = *(const short8*)(&outT[g * 8]);
}

// zero the halo ring of ONE buffer (schedule AFTER last reader of aliased layout)
__global__ void halo_zero_one(short* __restrict__ buf, int C) {
    int nchunk = C >> 3;
    int slot = blockIdx.x * 256 + threadIdx.x;
    int total = 8 * 772 * nchunk;
    if (slot >= total) return;
    int chunk = slot % nchunk;
    int pix = slot / nchunk;
    int b = pix / 772, p = pix % 772;
    int row, col;
    if (p < 516) { row = (p < 258) ? 0 : 129; col = (p < 258) ? p : p - 258; }
    else { int q = p - 516; row = 1 + (q >> 1); col = (q & 1) ? 257 : 0; }
    short8 z = {};
    *(short8*)(buf + ((size_t)(b * 130 + row) * 258 + col) * C + chunk * 8) = z;
}

// fp32 HWIO weights -> bf16 PADDED AFFINE layout, all 5 layers in one launch.
// Per dy-slice (ph = kc*3+dy): granule gs = (q*3 + dx)*(COUT+1) + n, holding
// k = kc*32 + q*8 + j (j=0..7) for output channel n at tap dy*3+dx.
// The +1 pad on n makes a 16-lane phase (q const, n=nt*16+col consecutive)
// read CONSECUTIVE granules -> conflict-free by construction AND the read
// address is base + dx*2064 + nt*256 (pure immediates; no per-read VALU).
// k zero-padded past CIN; n=COUT pad column is never read.
__global__ void wconv_all(const float* __restrict__ k1, const float* __restrict__ k2,
                          const float* __restrict__ k3, const float* __restrict__ k4,
                          const float* __restrict__ k5,
                          short* __restrict__ w1, short* __restrict__ w2,
                          short* __restrict__ w3, short* __restrict__ w4,
                          short* __restrict__ w5) {
    const int CINt[5]  = {134, 128, 128, 96, 64};
    const int COUTt[5] = {128, 128, 96, 64, 32};
    const int KCt[5]   = {5, 4, 4, 3, 2};
    const float* srcs[5] = {k1, k2, k3, k4, k5};
    short* dsts[5] = {w1, w2, w3, w4, w5};
    int l = blockIdx.y;
    int CIN = CINt[l], COUT = COUTt[l], KC = KCt[l];
    const float* k = srcs[l];
    short* wt = dsts[l];
    int WS = 4 * 3 * (COUT + 1);          // granules per dy-slice
    int total = KC * 3 * WS * 8;          // shorts
    int idx = blockIdx.x * 256 + threadIdx.x;
    if (idx >= total) return;
    int j = idx & 7;
    int g = idx >> 3;
    int ph = g / WS, gs = g % WS;
    int kc = ph / 3, dy = ph % 3;
    int n = gs % (COUT + 1);
    int g2 = gs / (COUT + 1);
    int dx = g2 % 3, qq = g2 / 3;
    int tap = dy * 3 + dx;
    int ci = kc * 32 + qq * 8 + j;
    float v = (n < COUT && ci < CIN) ? k[(size_t)(tap * CIN + ci) * COUT + n] : 0.f;
    wt[idx] = (short)f2b(v);
}

// 3x3 SAME conv, halo layout [B,130,258,CIN_STR] -> [B,130,258,COUT].
// r5 topology kept (best: 604.8us): 512 blocks x 8 waves; tile 8 rows x 64
// cols x COUT; wave = 1 row x 64 px x full COUT; acc[4][NT] (<=128 AGPR);
// A double-buffered + prefetched at kc top; __launch_bounds__(512,2).
// [r2/r6 proved 2 blocks/CU unreachable: 64-f32 acc spills at 128-reg cap.]
// CHANGES vs r5 (attack the measured 22% VALUBusy = ~6k cy/kc serial VALU):
//  * A layout [c][row(10)][p(67 padded)]: phase reads consecutive granules ->
//    conflict-free, and read addr = ONE base reg + imm (dy*1072+mt*256+dx*16).
//  * W layout [q][dx][n(COUT+1 padded)] per dy-slice, pre-baked in global ->
//    read addr = ONE base reg + imm (dx*2064+nt*256). No XOR swizzle anywhere.
//  * A-stage index decomposition (int div) hoisted ONCE pre-loop into 6 slot
//    regs; per kc the global addr just advances by kc*32.
//  * W staged per dy-slice, double-buffered, prefetched one phase ahead ->
//    exposed W stage (~1.3k cy/kc in r5) now hidden. LDS 135,296 B.
template <int KC, int CIN_STR, int COUT, int NT, int LASTC>
__launch_bounds__(512, 2)
__global__ void conv3x3_kernel(const short* __restrict__ in, const short* __restrict__ wt,
                               const float* __restrict__ bias, short* __restrict__ out) {
    const int AG = 4 * 10 * 67;              // 2680 A granules (42,880 B)
    const int WS = 4 * 3 * (COUT + 1);       // granules per W dy-slice
    __shared__ short ldsA[2][AG * 8];
    __shared__ short ldsW[2][WS * 8];

    int t = threadIdx.x;
    int lane = t & 63, wid = t >> 6;
    int q = lane >> 4, col = lane & 15;

    int wtile = blockIdx.x & 3;
    int rest = blockIdx.x >> 2;
    int htile = rest & 15, b = rest >> 4;
    int w0h = wtile << 6;                    // staged cols w0h .. w0h+65
    int row0 = htile << 3;                   // staged rows row0 .. row0+9

    const short* inbase = in + ((size_t)(b * 130 + row0) * 258 + w0h) * CIN_STR;

    // ---- per-thread A-stage slots, decomposed ONCE (i = t + s*512 fixed) ----
    int agoff[6], ac[6], avalid[6];
#pragma unroll
    for (int s = 0; s < 6; ++s) {
        int i = t + s * 512;
        int c = i / 670, rem = i % 670;
        int row = rem / 67, p = rem % 67;
        ac[s] = c;
        avalid[s] = (i < AG) && (p < 66);
        agoff[s] = (row * 258 + p) * CIN_STR + c * 8;
    }
    int ldst0 = (t & ~63) * 8;               // shorts; slot s adds s*512*8

    auto stageA = [&](int kc, int d) {
        short* dst = &ldsA[d][ldst0];
#pragma unroll
        for (int s = 0; s < 6; ++s) {
            if (avalid[s] && (LASTC == 4 || kc < KC - 1 || ac[s] < LASTC))
                async16(inbase + agoff[s] + kc * 32, dst + s * 512 * 8);
        }
    };
    auto stageW = [&](int ph, int d) {
        const short* src = wt + (size_t)ph * WS * 8;
        short* dst = &ldsW[d][ldst0];
#pragma unroll
        for (int s = 0; s < (WS + 511) / 512; ++s) {
            int i = t + s * 512;
            if (i < WS) async16(src + (size_t)i * 8, dst + s * 512 * 8);
        }
    };

    f32x4 acc[4][NT] = {};

    stageA(0, 0);
    stageW(0, 0);
    __syncthreads();

    int aoff = ((q * 10 + wid) * 67 + col) * 16;   // byte offset of A base
    int woff = (q * 3 * (COUT + 1) + col) * 16;    // byte offset of W base

    int wb = 0;
    for (int kc = 0; kc < KC; ++kc) {
        const char* Acur = (const char*)&ldsA[kc & 1][0] + aoff;
#pragma unroll
        for (int dy = 0; dy < 3; ++dy) {
            int ph = kc * 3 + dy;
            if (ph + 1 < 3 * KC) stageW(ph + 1, wb ^ 1);      // prefetch next W
            if (dy == 0 && kc + 1 < KC) stageA(kc + 1, (kc + 1) & 1);
            const char* ab = Acur + dy * 1072;                // +67 granules/row
            const char* wp = (const char*)&ldsW[wb][0] + woff;
#pragma unroll
            for (int dx = 0; dx < 3; ++dx) {
                short8 a[4], bfr[NT];
#pragma unroll
                for (int mt = 0; mt < 4; ++mt)
                    a[mt] = *(const short8*)(ab + dx * 16 + mt * 256);
#pragma unroll
                for (int nt = 0; nt < NT; ++nt)
                    bfr[nt] = *(const short8*)(wp + dx * (COUT + 1) * 16 + nt * 256);
#pragma unroll
                for (int mt = 0; mt < 4; ++mt)
#pragma unroll
                    for (int nt = 0; nt < NT; ++nt)
                        acc[mt][nt] = __builtin_amdgcn_mfma_f32_16x16x32_bf16(
                            a[mt], bfr[nt], acc[mt][nt], 0, 0, 0);
            }
            __syncthreads();   // prev readers done; prefetched W/A drained (issued
            wb ^= 1;           // a full phase ago -> drain is free)
        }
    }

    // ---- epilogue: D[m = mt*16 + q*4 + rr][n = nt*16 + col], leaky-relu, bf16 ----
    size_t obase = ((size_t)(b * 130 + row0 + 1 + wid) * 258 + (w0h + 1)) * COUT;
#pragma unroll
    for (int nt = 0; nt < NT; ++nt) {
        int n = nt * 16 + col;
        float bv = bias[n];
#pragma unroll
        for (int mt = 0; mt < 4; ++mt) {
#pragma unroll
            for (int rr = 0; rr < 4; ++rr) {
                int m = mt * 16 + q * 4 + rr;
                float v = acc[mt][nt][rr] + bv;
                v = (v >= 0.f) ? v : LEAK * v;
                out[obase + (size_t)m * COUT + n] = (short)f2b(v);
            }
        }
    }
}

// conv6: 3x3, Cin=32 (halo layout), Cout=1, linear, fp32 out (flat [B,H,W])
__global__ void conv6_kernel(const short* __restrict__ x, const float* __restrict__ k,
                             const float* __restrict__ bias, float* __restrict__ out) {
    __shared__ float wk[288];
    int t = threadIdx.x;
    for (int i = t; i < 288; i += 256) wk[i] = k[i];
    __syncthreads();
    int idx = blockIdx.x * 256 + t;
    int w = idx & 255, h = (idx >> 8) & 127, b = idx >> 15;
    float acc = bias[0];
#pragma unroll
    for (int dy = 0; dy < 3; ++dy) {
#pragma unroll
        for (int dx = 0; dx < 3; ++dx) {
            const short* xp = x + ((size_t)(b * 130 + h + dy) * 258 + (w + dx)) * 32;
            const float* wp = wk + (dy * 3 + dx) * 32;
#pragma unroll
            for (int c8 = 0; c8 < 4; ++c8) {
                short8 v = *(const short8*)(xp + c8 * 8);
#pragma unroll
                for (int j = 0; j < 8; ++j)
                    acc += b2f((unsigned short)v[j]) * wp[c8 * 8 + j];
            }
        }
    }
    out[idx] = acc;
}

extern "C" void kernel_launch(void* const* d_in, const int* in_sizes, int n_in,
                              void* d_out, int out_size, void* d_ws, size_t ws_size,
                              hipStream_t stream) {
    const float* left  = (const float*)d_in[0];
    const float* right = (const float*)d_in[1];
    const float* pd    = (const float*)d_in[2];
    const float* k[6];
    const float* bb[6];
    for (int i = 0; i < 6; ++i) { k[i] = (const float*)d_in[3 + 2 * i]; bb[i] = (const float*)d_in[4 + 2 * i]; }

    char* ws = (char*)d_ws;
    // weights (padded affine layout): sizes KC*3*4*3*(COUT+1)*16 B
    // L1 371,520 | L2 297,216 | L3 223,488 | L4 112,320 | L5 38,016 -> 1,042,560 < 1 MiB
    short* wt1 = (short*)ws;
    short* wt2 = (short*)(ws + 371520);
    short* wt3 = (short*)(ws + 668736);
    short* wt4 = (short*)(ws + 892224);
    short* wt5 = (short*)(ws + 1004544);
    // region A @1 MiB: vol(C=144) -> X2(128) -> X4(64); region B: X1(128) -> X3(96) -> X5(32)
    short* vol = (short*)(ws + 1048576);
    short* X1  = (short*)(ws + 1048576 + 77276160);
    short* X2  = vol;
    short* X3  = X1;
    short* X4  = vol;
    short* X5  = X1;

    auto hz = [&](short* buf, int C) {
        int blocks = (8 * 772 * (C >> 3) + 255) / 256;
        halo_zero_one<<<blocks, 256, 0, stream>>>(buf, C);
    };

    prep_kernel<<<4096, 256, 0, stream>>>(left, right, pd, vol);
    wconv_all<<<dim3(726, 5), 256, 0, stream>>>(k[0], k[1], k[2], k[3], k[4],
                                                wt1, wt2, wt3, wt4, wt5);
    hz(vol, 144);
    hz(X1, 128);

    conv3x3_kernel<5, 144, 128, 8, 2><<<512, 512, 0, stream>>>(vol, wt1, bb[0], X1);
    hz(X2, 128);   // region A: only after conv1 finished reading vol
    conv3x3_kernel<4, 128, 128, 8, 4><<<512, 512, 0, stream>>>(X1, wt2, bb[1], X2);
    hz(X3, 96);    // region B: only after conv2 finished reading X1
    conv3x3_kernel<4, 128,  96, 6, 4><<<512, 512, 0, stream>>>(X2, wt3, bb[2], X3);
    hz(X4, 64);    // region A: only after conv3 finished reading X2
    conv3x3_kernel<3,  96,  64, 4, 4><<<512, 512, 0, stream>>>(X3, wt4, bb[3], X4);
    hz(X5, 32);    // region B: only after conv4 finished reading X3
    conv3x3_kernel<2,  64,  32, 2, 4><<<512, 512, 0, stream>>>(X4, wt5, bb[4], X5);
    conv6_kernel<<<1024, 256, 0, stream>>>(X5, k[5], bb[5], (float*)d_out);
}

// Round 8
// 621.140 us; speedup vs baseline: 1.1693x; 1.0793x over previous
//
#include <hip/hip_runtime.h>

typedef __attribute__((ext_vector_type(8))) short short8;
typedef __attribute__((ext_vector_type(4))) float f32x4;
typedef __attribute__((ext_vector_type(4))) unsigned short us4;

#define LEAK 0.2f

__device__ __forceinline__ float b2f(unsigned short s) {
    unsigned u = ((unsigned)s) << 16;
    return __builtin_bit_cast(float, u);
}
__device__ __forceinline__ unsigned short f2b(float f) {
    unsigned u = __builtin_bit_cast(unsigned, f);
    u += 0x7fffu + ((u >> 16) & 1u);
    return (unsigned short)(u >> 16);
}

// async 16B global->LDS (direct-to-shared DMA). LDS base wave-uniform; HW adds lane*16.
__device__ __forceinline__ void async16(const short* g, short* l) {
    __builtin_amdgcn_global_load_lds(
        (const __attribute__((address_space(1))) void*)g,
        (__attribute__((address_space(3))) void*)l, 16, 0, 0);
}

// ---------------- prep: upsample / warp / cost volume (LDS-staged, coalesced) ----
// Block = 64 pixels of one row (quarter row). All global I/O is 16B/lane contiguous.
// vol: halo layout [B,130,258,144] bf16; interior pixel (h,w) -> row h+1, col w+1.
// ch 0..127 = left(bf16), 128..132 = costs, 133 = up, 134..143 = 0.
__global__ __launch_bounds__(256)
void prep_kernel(const float* __restrict__ left, const float* __restrict__ right,
                 const float* __restrict__ pd, short* __restrict__ vol) {
    __shared__ __align__(16) float inL[64 * 132];   // [px][128 ch + 4 pad]
    __shared__ __align__(16) float rrow[256];       // right row (b,h)
    __shared__ __align__(16) float pr0[128];        // pd row y0c
    __shared__ __align__(16) float pr1[128];        // pd row y1c
    __shared__ __align__(16) short outT[64 * 144];  // output tile

    int t = threadIdx.x;
    int blk = blockIdx.x;                 // 4096 = b(8) * h(128) * wq(4)
    int wq = blk & 3, h = (blk >> 2) & 127, b = blk >> 9;
    int w0 = wq << 6;

    // row-uniform upsample y terms
    float sy = h * 0.5f - 0.25f;
    float fy0 = floorf(sy);
    float fy = sy - fy0;
    int y0 = (int)fy0;
    int y0c = min(max(y0, 0), 63), y1c = min(max(y0 + 1, 0), 63);

    // ---- phase 1: coalesced loads -> LDS ----
    const float* lp = left + ((size_t)((b * 128 + h) * 256 + w0)) * 128;
#pragma unroll
    for (int k2 = 0; k2 < 8; ++k2) {
        int g = t + k2 * 256;             // granule 0..2047 (16B each)
        int p = g >> 5, j = g & 31;
        float4 v = *(const float4*)(lp + (size_t)g * 4);
        *(float4*)(&inL[p * 132 + j * 4]) = v;
    }
    if (t < 64) {
        *(float4*)(&rrow[t * 4]) =
            *(const float4*)(right + ((size_t)(b * 128 + h)) * 256 + t * 4);
    } else if (t < 96) {
        int i2 = t - 64;
        *(float4*)(&pr0[i2 * 4]) = *(const float4*)(pd + (size_t)(b * 64 + y0c) * 128 + i2 * 4);
    } else if (t < 128) {
        int i2 = t - 96;
        *(float4*)(&pr1[i2 * 4]) = *(const float4*)(pd + (size_t)(b * 64 + y1c) * 128 + i2 * 4);
    }
    __syncthreads();

    // ---- phase 2: 4 threads per pixel ----
    int p = t >> 2, s = t & 3;
    int w = w0 + p;
    const float* src = &inL[p * 132 + s * 32];
    short* odst = &outT[p * 144 + s * 32];
    float sum = 0.f;
#pragma unroll
    for (int i = 0; i < 8; ++i) {
        float f0 = src[i * 4], f1 = src[i * 4 + 1], f2 = src[i * 4 + 2], f3 = src[i * 4 + 3];
        sum += (f0 + f1) + (f2 + f3);
        us4 o;
        o.x = f2b(f0); o.y = f2b(f1); o.z = f2b(f2); o.w = f2b(f3);
        *(us4*)(odst + i * 4) = o;
    }
    sum += __shfl_xor(sum, 1);
    sum += __shfl_xor(sum, 2);
    float mean = sum * (1.f / 128.f);

    float one_fy = 1.f - fy;
#pragma unroll
    for (int tap = s; tap < 5; tap += 4) {   // s=0 -> taps 0,4; s=1,2,3 -> taps 1,2,3
        int jj = w + tap - 2;
        if (jj >= 0 && jj < 256) {
            float sx = jj * 0.5f - 0.25f;
            float fx0 = floorf(sx);
            float fx = sx - fx0;
            int x0 = (int)fx0;
            int x0c = min(max(x0, 0), 127), x1c = min(max(x0 + 1, 0), 127);
            float up = one_fy * ((1.f - fx) * pr0[x0c] + fx * pr0[x1c])
                     + fy     * ((1.f - fx) * pr1[x0c] + fx * pr1[x1c]);
            float cx = (float)jj - up;
            float xf0 = floorf(cx), xf1 = xf0 + 1.f;
            float w0x = xf1 - cx, w1x = cx - xf0;
            int ix0 = (int)fminf(fmaxf(xf0, 0.f), 255.f);
            int ix1 = (int)fminf(fmaxf(xf1, 0.f), 255.f);
            float warped = w0x * rrow[ix0] + w1x * rrow[ix1];
            outT[p * 144 + 128 + tap] = (short)f2b(warped * mean);
            if (tap == 2) outT[p * 144 + 133] = (short)f2b(up);   // jj==w always in-range
        } else {
            outT[p * 144 + 128 + tap] = 0;
        }
    }
    if (s == 0) { outT[p * 144 + 134] = 0; outT[p * 144 + 135] = 0; }
    if (s == 3) {
        us4 z = {};
        *(us4*)(&outT[p * 144 + 136]) = z;
        *(us4*)(&outT[p * 144 + 140]) = z;
    }
    __syncthreads();

    // ---- phase 3: coalesced store (tile is contiguous in halo layout) ----
    short* gdst = vol + ((size_t)(b * 130 + h + 1) * 258 + (w0 + 1)) * 144;
    for (int g = t; g < 1152; g += 256)
        *(short8*)(gdst + g * 8) = *(const short8*)(&outT[g * 8]);
}

// zero the halo ring of ONE buffer (schedule AFTER last reader of aliased layout)
__global__ void halo_zero_one(short* __restrict__ buf, int C) {
    int nchunk = C >> 3;
    int slot = blockIdx.x * 256 + threadIdx.x;
    int total = 8 * 772 * nchunk;
    if (slot >= total) return;
    int chunk = slot % nchunk;
    int pix = slot / nchunk;
    int b = pix / 772, p = pix % 772;
    int row, col;
    if (p < 516) { row = (p < 258) ? 0 : 129; col = (p < 258) ? p : p - 258; }
    else { int q = p - 516; row = 1 + (q >> 1); col = (q & 1) ? 257 : 0; }
    short8 z = {};
    *(short8*)(buf + ((size_t)(b * 130 + row) * 258 + col) * C + chunk * 8) = z;
}

// fp32 HWIO weights -> bf16 swizzled layout, all 5 layers in one launch.
// Layout (shorts): granule g = ((kc*9+tap)*COUT + n)*4 + s, where slot s holds
// k-quarter q = (s - (n>>1)) & 3; within granule, 8 consecutive k (q*8..q*8+7).
// k zero-padded past CIN. Staged to LDS as identity copy (legal for
// global_load_lds); read with slot=(q+(n>>1))&3.
// WHY >>1: LDS serves a wave64 ds_read_b128 in quarter-wave phases of 16 lanes
// with q CONSTANT inside a phase; granule%8 = 4*(n&1) + slot must walk all 8
// bank groups as col=n&15 varies. slot=(q+(n>>1))&3 does; slot=(q+n)&3 and
// plain consecutive-granule layouts do NOT (r0/r7: 8.85M conflict cycles;
// r4/r5 with >>1: exactly 0).
__global__ void wconv_all(const float* __restrict__ k1, const float* __restrict__ k2,
                          const float* __restrict__ k3, const float* __restrict__ k4,
                          const float* __restrict__ k5,
                          short* __restrict__ w1, short* __restrict__ w2,
                          short* __restrict__ w3, short* __restrict__ w4,
                          short* __restrict__ w5) {
    const int CINt[5]  = {134, 128, 128, 96, 64};
    const int COUTt[5] = {128, 128, 96, 64, 32};
    const int KCt[5]   = {5, 4, 4, 3, 2};
    const float* srcs[5] = {k1, k2, k3, k4, k5};
    short* dsts[5] = {w1, w2, w3, w4, w5};
    int l = blockIdx.y;
    int CIN = CINt[l], COUT = COUTt[l], KC = KCt[l];
    const float* k = srcs[l];
    short* wt = dsts[l];
    int idx = blockIdx.x * 256 + threadIdx.x;
    int total = 9 * KC * COUT * 32;
    if (idx >= total) return;
    int j = idx & 7;
    int s = (idx >> 3) & 3;
    int rest = idx >> 5;              // (kc*9+tap)*COUT + n
    int n = rest % COUT; rest /= COUT;
    int tap = rest % 9, kc = rest / 9;
    int q = (s - (n >> 1)) & 3;
    int kk = q * 8 + j;
    int ci = kc * 32 + kk;
    float v = (ci < CIN) ? k[(size_t)(tap * CIN + ci) * COUT + n] : 0.f;
    wt[idx] = (short)f2b(v);
}

// 3x3 SAME conv, halo layout [B,130,258,CIN_STR] -> [B,130,258,COUT].
// Base = round 5 (best, 604.8us): 512 blocks x 8 waves; tile 8 rows x 64 cols
// x COUT; wave = 1 row x 64 px x full COUT; acc[4][NT] (AGPR); A dbuf
// prefetched at kc top; full-kc W stage; __launch_bounds__(512,2); the
// r4/r5-verified zero-conflict >>1 XOR layouts for BOTH A and W.
// CHANGES vs r5 (attack the 22% VALUBusy, using r7's separately-verified
// techniques, NO layout change):
//  * Affine decomposition of the swizzled reads: since mt*16 is even and
//    mt*8 = 0 (mod 4), A's swizzle (q+(p>>1))&3 with p=mt*16+col+dx depends
//    only on (col+dx) -> 3 hoisted base regs + immediates dy*4224 + mt*1024.
//    W's swizzle (q+(n>>1))&3 with n=nt*16+col depends only on col -> 1
//    hoisted base reg + immediates dx*COUT*64 + nt*1024 (dy folded into a
//    per-dy pointer to respect the 16-bit ds offset limit).
//  * A-stage index decomposition (int div/mod) hoisted ONCE pre-loop into 6
//    offset regs + 2 packed predicate masks; per kc the addr advances kc*32.
// r7 measured 124 VGPR with MORE hoisted state -> 124+128 acc = 252 <= 256,
// still 2 waves/SIMD.
template <int KC, int CIN_STR, int COUT, int NT, int LASTC>
__launch_bounds__(512, 2)
__global__ void conv3x3_kernel(const short* __restrict__ in, const short* __restrict__ wt,
                               const float* __restrict__ bias, short* __restrict__ out) {
    __shared__ short ldsA[2][10 * 66 * 4 * 8];   // 2 x 42,240 B
    __shared__ short ldsW[9 * COUT * 32];        // COUT=128: 73,728 B
    const int AG = 10 * 66 * 4;                  // 2640 A granules
    const int WSLOTS = 9 * COUT * 4;             // 16B granules in the W slice
    const int WSTRIDE = 9 * COUT * 32;           // shorts per kc slice

    int t = threadIdx.x;
    int lane = t & 63, wid = t >> 6;
    int q = lane >> 4, col = lane & 15;

    int wtile = blockIdx.x & 3;
    int rest = blockIdx.x >> 2;
    int htile = rest & 15, b = rest >> 4;
    int w0h = wtile << 6;                        // staged cols w0h .. w0h+65
    int row0 = htile << 3;                       // staged rows row0 .. row0+9

    const short* inbase = in + ((size_t)(b * 130 + row0) * 258 + w0h) * CIN_STR;

    // ---- hoisted A-stage decomposition (once; r5 recomputed i/264 per kc) ----
    // granule i = rr*264 + p*4 + s; slot s holds channel-chunk c=(s-(p>>1))&3
    int agoff[6];
    unsigned maskAll = 0, maskLast = 0;
#pragma unroll
    for (int sl = 0; sl < 6; ++sl) {
        int i = t + sl * 512;
        int rr = i / 264, rem = i % 264;
        int p = rem >> 2, s = rem & 3;
        int c = (s - (p >> 1)) & 3;
        agoff[sl] = (rr * 258 + p) * CIN_STR + c * 8;
        if (i < AG) {
            maskAll |= 1u << sl;
            if (LASTC == 4 || c < LASTC) maskLast |= 1u << sl;
        }
    }
    int ldst0 = (t & ~63) * 8;                   // shorts; slot sl adds sl*4096

    auto stageA = [&](int kc, int d) {
        short* dst = &ldsA[d][ldst0];
        unsigned m = (kc == KC - 1) ? maskLast : maskAll;
#pragma unroll
        for (int sl = 0; sl < 6; ++sl) {
            if ((m >> sl) & 1)
                async16(inbase + agoff[sl] + kc * 32, dst + sl * 4096);
        }
    };
    auto stageW = [&](int kc) {
        const short* wsrc = wt + (size_t)kc * WSTRIDE;
        short* dst = ldsW + ldst0;
#pragma unroll
        for (int sl = 0; sl < (WSLOTS + 511) / 512; ++sl) {
            int i = t + sl * 512;
            if (i < WSLOTS) async16(wsrc + (size_t)i * 8, dst + sl * 4096);
        }
    };

    // ---- hoisted affine read bases (byte offsets; layout identical to r5) ----
    int abase[3];
#pragma unroll
    for (int dx = 0; dx < 3; ++dx) {
        int pc = col + dx;
        abase[dx] = (wid * 264 + 4 * pc + ((q + (pc >> 1)) & 3)) * 16;
    }
    int wbase = (4 * col + ((q + (col >> 1)) & 3)) * 16;

    f32x4 acc[4][NT] = {};

    stageW(0);
    stageA(0, 0);
    __syncthreads();

    for (int kc = 0; kc < KC; ++kc) {
        // prefetch next A chunk; it has the whole compute phase to land
        if (kc + 1 < KC) stageA(kc + 1, (kc + 1) & 1);
        const char* A = (const char*)&ldsA[kc & 1][0];

#pragma unroll
        for (int dy = 0; dy < 3; ++dy) {
            const char* arow = A + dy * 4224;                 // +264 granules/row
            const char* wrow = (const char*)ldsW + wbase + dy * 3 * COUT * 64;
#pragma unroll
            for (int dx = 0; dx < 3; ++dx) {
                short8 a[4], bfr[NT];
#pragma unroll
                for (int mt = 0; mt < 4; ++mt)
                    a[mt] = *(const short8*)(arow + abase[dx] + mt * 1024);
#pragma unroll
                for (int nt = 0; nt < NT; ++nt)
                    bfr[nt] = *(const short8*)(wrow + dx * COUT * 64 + nt * 1024);
#pragma unroll
                for (int mt = 0; mt < 4; ++mt)
#pragma unroll
                    for (int nt = 0; nt < NT; ++nt)
                        acc[mt][nt] = __builtin_amdgcn_mfma_f32_16x16x32_bf16(
                            a[mt], bfr[nt], acc[mt][nt], 0, 0, 0);
            }
        }
        __syncthreads();                 // drains A(kc+1) prefetch: free by now
        if (kc + 1 < KC) {
            stageW(kc + 1);              // L2-resident, ~1.3k cy exposed
            __syncthreads();
        }
    }

    // ---- epilogue: D[m = mt*16 + q*4 + rr][n = nt*16 + col], leaky-relu, bf16 ----
    size_t obase = ((size_t)(b * 130 + row0 + 1 + wid) * 258 + (w0h + 1)) * COUT;
#pragma unroll
    for (int nt = 0; nt < NT; ++nt) {
        int n = nt * 16 + col;
        float bv = bias[n];
#pragma unroll
        for (int mt = 0; mt < 4; ++mt) {
#pragma unroll
            for (int rr = 0; rr < 4; ++rr) {
                int m = mt * 16 + q * 4 + rr;
                float v = acc[mt][nt][rr] + bv;
                v = (v >= 0.f) ? v : LEAK * v;
                out[obase + (size_t)m * COUT + n] = (short)f2b(v);
            }
        }
    }
}

// conv6: 3x3, Cin=32 (halo layout), Cout=1, linear, fp32 out (flat [B,H,W])
__global__ void conv6_kernel(const short* __restrict__ x, const float* __restrict__ k,
                             const float* __restrict__ bias, float* __restrict__ out) {
    __shared__ float wk[288];
    int t = threadIdx.x;
    for (int i = t; i < 288; i += 256) wk[i] = k[i];
    __syncthreads();
    int idx = blockIdx.x * 256 + t;
    int w = idx & 255, h = (idx >> 8) & 127, b = idx >> 15;
    float acc = bias[0];
#pragma unroll
    for (int dy = 0; dy < 3; ++dy) {
#pragma unroll
        for (int dx = 0; dx < 3; ++dx) {
            const short* xp = x + ((size_t)(b * 130 + h + dy) * 258 + (w + dx)) * 32;
            const float* wp = wk + (dy * 3 + dx) * 32;
#pragma unroll
            for (int c8 = 0; c8 < 4; ++c8) {
                short8 v = *(const short8*)(xp + c8 * 8);
#pragma unroll
                for (int j = 0; j < 8; ++j)
                    acc += b2f((unsigned short)v[j]) * wp[c8 * 8 + j];
            }
        }
    }
    out[idx] = acc;
}

extern "C" void kernel_launch(void* const* d_in, const int* in_sizes, int n_in,
                              void* d_out, int out_size, void* d_ws, size_t ws_size,
                              hipStream_t stream) {
    const float* left  = (const float*)d_in[0];
    const float* right = (const float*)d_in[1];
    const float* pd    = (const float*)d_in[2];
    const float* k[6];
    const float* bb[6];
    for (int i = 0; i < 6; ++i) { k[i] = (const float*)d_in[3 + 2 * i]; bb[i] = (const float*)d_in[4 + 2 * i]; }

    char* ws = (char*)d_ws;
    // weights: [0, 1 MiB)
    short* wt1 = (short*)ws;
    short* wt2 = (short*)(ws + 368640);
    short* wt3 = (short*)(ws + 663552);
    short* wt4 = (short*)(ws + 884736);
    short* wt5 = (short*)(ws + 995328);
    // region A @1 MiB: vol(C=144) -> X2(128) -> X4(64); region B: X1(128) -> X3(96) -> X5(32)
    short* vol = (short*)(ws + 1048576);
    short* X1  = (short*)(ws + 1048576 + 77276160);
    short* X2  = vol;
    short* X3  = X1;
    short* X4  = vol;
    short* X5  = X1;

    auto hz = [&](short* buf, int C) {
        int blocks = (8 * 772 * (C >> 3) + 255) / 256;
        halo_zero_one<<<blocks, 256, 0, stream>>>(buf, C);
    };

    prep_kernel<<<4096, 256, 0, stream>>>(left, right, pd, vol);
    wconv_all<<<dim3(720, 5), 256, 0, stream>>>(k[0], k[1], k[2], k[3], k[4],
                                                wt1, wt2, wt3, wt4, wt5);
    hz(vol, 144);
    hz(X1, 128);

    conv3x3_kernel<5, 144, 128, 8, 2><<<512, 512, 0, stream>>>(vol, wt1, bb[0], X1);
    hz(X2, 128);   // region A: only after conv1 finished reading vol
    conv3x3_kernel<4, 128, 128, 8, 4><<<512, 512, 0, stream>>>(X1, wt2, bb[1], X2);
    hz(X3, 96);    // region B: only after conv2 finished reading X1
    conv3x3_kernel<4, 128,  96, 6, 4><<<512, 512, 0, stream>>>(X2, wt3, bb[2], X3);
    hz(X4, 64);    // region A: only after conv3 finished reading X2
    conv3x3_kernel<3,  96,  64, 4, 4><<<512, 512, 0, stream>>>(X3, wt4, bb[3], X4);
    hz(X5, 32);    // region B: only after conv4 finished reading X3
    conv3x3_kernel<2,  64,  32, 2, 4><<<512, 512, 0, stream>>>(X4, wt5, bb[4], X5);
    conv6_kernel<<<1024, 256, 0, stream>>>(X5, k[5], bb[5], (float*)d_out);
}